// Round 1
// 114.397 us; speedup vs baseline: 1.0972x; 1.0972x over previous
//
#include <hip/hip_runtime.h>

// binary_decoder: bit-exact float32 emulation of the reference's sequential
// carry-save adder.
//
// Round-5 changes (diagnosis: csa_main is dependence-latency bound at
// ~61 cy/step while the true dependence cycle is only ~4 VALU links;
// VALUBusy 28% == 18 issue-cy / 61 cy period. The compiler emitted a
// serial per-step walk: (a) program order placed the cndmask(h)->dpp tail
// of step i before the independent uu of step i+1, (b) the 128-VGPR
// per-lane x buffer (xb[4][8] float4) left no registers for cross-step
// pipelining):
//  - dpp rotated across the step boundary: keep h (pre-shift carry) as
//    loop state; compute cn = dpp(h_prev) at the TOP of each step. Input
//    is 4+ instrs old (no VGPR->DPP hazard stall) and dpp latency overlaps
//    the independent uu = s + a. Identical ops, identical order, identical
//    values -- only the schedule-friendly placement changes.
//  - x is wave-uniform per step: store lane-sliced (1 VGPR per 64 steps,
//    lane l holds x[f0+l]) and broadcast with v_readlane (const lane).
//    Kills 128 VGPRs of duplicated x and cuts VMEM to 3 loads / 64 steps.
//
// Exactness of the chain (unchanged): a = bit ? x : +0 via sign-extended
// mask AND (x >= 0); uu = fp32(s+a); t = fp32(uu+cn) matches the reference
// association; t < 4 so floor(t/2) = (t>=2); s' = t-2 exact on [2,4).
// Carry via DPP row_shr:1 of h, h pre-masked to 0 on MSB lanes (kmask);
// with h as state, c_i = dpp(h_{i-1}), h init 0 -> c_0 = 0, final
// c = dpp(h_last). Same op sequence as rounds 1-4 (absmax 0.0 verified).

#define F_DIM 2048
#define K_DIM 4096
#define B_DIM 8
#define G     32            // steps per group = bits per packed dword
#define NG    (F_DIM / G)   // 64 groups
#define NSB   (F_DIM / 64)  // 32 superblocks of 64 steps

#define PK_BYTES (64 * NG * 64 * 4)  // 1 MB: [og][f32][lane] dwords

__device__ __forceinline__ float dpp_row_shr1(float v) {
    // row_shr:1 (0x111), all rows/banks, bound_ctrl: out-of-row source -> 0
    int r = __builtin_amdgcn_update_dpp(0, __float_as_int(v), 0x111, 0xf, 0xf, true);
    return __int_as_float(r);
}

__device__ __forceinline__ int sext_bit(unsigned bits, int u) {
#if __has_builtin(__builtin_amdgcn_sbfe)
    return __builtin_amdgcn_sbfe((int)bits, (unsigned)u, 1u);  // v_bfe_i32
#else
    return ((int)(bits << (31 - u))) >> 31;
#endif
}

// ---------------- pass 1: pack (w >= 0.5) bits -----------------------------
// pk[(og*64 + f32)*64 + lane] bit j = (w[(f32*32+j)][og*64+lane] >= 0.5)
__global__ __launch_bounds__(64) void pack_kernel(const float* __restrict__ w,
                                                  unsigned* __restrict__ pk) {
    const int lane = threadIdx.x;      // 0..63 -> column within og
    const int og   = blockIdx.x;       // 0..63
    const int f32  = blockIdx.y;       // 0..63
    const float* wp = w + og * 64 + lane;
    unsigned bits = 0;
#pragma unroll
    for (int j = 0; j < 32; ++j) {
        float wv = wp[(f32 * 32 + j) * K_DIM];   // coalesced 256B per j
        bits |= (wv >= 0.5f ? 1u : 0u) << j;
    }
    pk[(og * 64 + f32) * 64 + lane] = bits;
}

// ---------------- pass 2: the sequential chain -----------------------------
__global__ __launch_bounds__(64, 1) void csa_main(const float* __restrict__ x,
                                                  const unsigned* __restrict__ pk,
                                                  float* __restrict__ out) {
    const int lane = threadIdx.x;                 // 0..63
    const int og   = blockIdx.x + 8 * blockIdx.y; // 0..63
    const int b    = blockIdx.z;                  // 0..7
    const int k    = og * 64 + lane;

    // 1.0 everywhere except the MSB bit-lane of each chain.
    const float kmask = ((lane & 7) == 7) ? 0.0f : 1.0f;

    const unsigned* bp = pk + og * (NG * 64) + lane;     // +64 per 32-step group
    const int*      xp = (const int*)(x + b * F_DIM) + lane; // +64 per superblock

    // Double-buffered superblock state, all names static (no runtime indexing).
    unsigned pkA0 = bp[0 * 64], pkA1 = bp[1 * 64];
    int      xA   = xp[0 * 64];
    unsigned pkB0 = bp[2 * 64], pkB1 = bp[3 * 64];
    int      xB   = xp[1 * 64];

    float s = 0.0f;
    float h = 0.0f;   // pre-shift carry state; c_i = dpp(h_{i-1}), h0=0 -> c0=0

    // 64 exact chain steps from two pk dwords + one lane-sliced x dword.
#define STEP64(PK0, PK1, XV)                                              \
    _Pragma("unroll")                                                      \
    for (int u = 0; u < 64; ++u) {                                         \
        int      xs   = __builtin_amdgcn_readlane((XV), u);                \
        unsigned bits = (u < 32) ? (PK0) : (PK1);                          \
        int      m    = sext_bit(bits, u & 31);                            \
        float    a    = __int_as_float(m & xs);   /* == x*hard, x >= 0 */  \
        float    cn   = dpp_row_shr1(h);          /* carry-in, input old */ \
        float    uu   = s + a;                    /* overlaps dpp */        \
        float    t    = uu + cn;                                           \
        bool     ge   = (t >= 2.0f);                                       \
        h = ge ? kmask : 0.0f;                                             \
        s = ge ? (t - 2.0f) : t;                                           \
    }

    for (int sb = 0; sb < NSB; sb += 2) {   // 16 iterations, 128 steps each
        STEP64(pkA0, pkA1, xA);
        {   // refill slot A for superblock sb+2 (clamped tail re-read, harmless)
            int nsb = sb + 2; int csb = (nsb < NSB) ? nsb : (NSB - 2);
            pkA0 = bp[(2 * csb + 0) * 64];
            pkA1 = bp[(2 * csb + 1) * 64];
            xA   = xp[csb * 64];
        }
        STEP64(pkB0, pkB1, xB);
        {   // refill slot B for superblock sb+3
            int nsb = sb + 3; int csb = (nsb < NSB) ? nsb : (NSB - 2);
            pkB0 = bp[(2 * csb + 0) * 64];
            pkB1 = bp[(2 * csb + 1) * 64];
            xB   = xp[csb * 64];
        }
    }
#undef STEP64

    float cfin = dpp_row_shr1(h);   // reference returns the post-shift carry
    out[b * K_DIM + k]                 = s;
    out[B_DIM * K_DIM + b * K_DIM + k] = cfin;
}

// ---------------- fallback (direct-w kernel) if ws is too small ------------
#define U_FB  16
#define NB_FB 4
__global__ __launch_bounds__(64, 1) void csa_fallback(const float* __restrict__ x,
                                                      const float* __restrict__ weight,
                                                      float* __restrict__ out) {
    const int lane = threadIdx.x;
    const int og   = blockIdx.x + 8 * blockIdx.y;
    const int b    = blockIdx.z;
    const int k    = og * 64 + lane;
    const float kmask = ((lane & 7) == 7) ? 0.0f : 1.0f;
    int zero;
    asm volatile("v_mov_b32 %0, 0" : "=v"(zero));
    const float*  wp  = weight + k;
    const float4* xp4 = (const float4*)(x + b * F_DIM) + zero;
    float  wb[NB_FB][U_FB];
    float4 xb[NB_FB][U_FB / 4];
#pragma unroll
    for (int p = 0; p < NB_FB; ++p) {
#pragma unroll
        for (int u = 0; u < U_FB; ++u) wb[p][u] = wp[(p * U_FB + u) * K_DIM];
#pragma unroll
        for (int q = 0; q < U_FB / 4; ++q) xb[p][q] = xp4[(p * U_FB) / 4 + q];
    }
    float s = 0.0f, c = 0.0f;
    for (int f0 = 0; f0 < F_DIM; f0 += NB_FB * U_FB) {
#pragma unroll
        for (int p = 0; p < NB_FB; ++p) {
            const float* xf = (const float*)&xb[p][0];
#pragma unroll
            for (int u = 0; u < U_FB; ++u) {
                float a  = (wb[p][u] >= 0.5f) ? xf[u] : 0.0f;
                float uu = s + a;
                float t  = uu + c;
                bool  ge = (t >= 2.0f);
                float hh = ge ? kmask : 0.0f;
                s = ge ? (t - 2.0f) : t;
                c = dpp_row_shr1(hh);
            }
            int fb = f0 + p * U_FB + NB_FB * U_FB;
            int fc = (fb <= F_DIM - U_FB) ? fb : (F_DIM - U_FB);
#pragma unroll
            for (int u = 0; u < U_FB; ++u) wb[p][u] = wp[(fc + u) * K_DIM];
#pragma unroll
            for (int q = 0; q < U_FB / 4; ++q) xb[p][q] = xp4[fc / 4 + q];
        }
    }
    out[b * K_DIM + k]                 = s;
    out[B_DIM * K_DIM + b * K_DIM + k] = c;
}

extern "C" void kernel_launch(void* const* d_in, const int* in_sizes, int n_in,
                              void* d_out, int out_size, void* d_ws, size_t ws_size,
                              hipStream_t stream) {
    (void)in_sizes; (void)n_in; (void)out_size;
    const float* x      = (const float*)d_in[0];
    const float* weight = (const float*)d_in[1];
    float* out          = (float*)d_out;

    if (ws_size >= (size_t)PK_BYTES && d_ws != nullptr) {
        unsigned* pk = (unsigned*)d_ws;
        pack_kernel<<<dim3(64, 64, 1), dim3(64), 0, stream>>>(weight, pk);
        csa_main<<<dim3(8, 8, 8), dim3(64), 0, stream>>>(x, pk, out);
    } else {
        csa_fallback<<<dim3(8, 8, 8), dim3(64), 0, stream>>>(x, weight, out);
    }
}